// Round 1
// baseline (469.791 us; speedup 1.0000x reference)
//
#include <hip/hip_runtime.h>

// Problem constants
#define NBLK 256   // batch blocks
#define NN   512   // nodes per block
#define DIN  256
#define DH   256
#define DOUT 128

typedef __attribute__((ext_vector_type(8))) short short8;
typedef __attribute__((ext_vector_type(4))) float f32x4;

__device__ __forceinline__ unsigned short f2bf(float x) {
  unsigned u = __float_as_uint(x);
  unsigned r = u + 0x7fffu + ((u >> 16) & 1u);
  return (unsigned short)(r >> 16);
}
__device__ __forceinline__ float bf2f(unsigned short b) {
  return __uint_as_float(((unsigned)b) << 16);
}

#define GLDS(g, l) __builtin_amdgcn_global_load_lds( \
    (const __attribute__((address_space(1))) void*)(g), \
    (__attribute__((address_space(3))) void*)(l), 16, 0, 0)

// ---------------------------------------------------------------------------
// feat (131072,256) fp32 -> Xbuf bf16, plus nz[row] = (||feat_row|| > 0)
// one wave per row (64 lanes x float4 = 256)
__global__ void k_feat(const float* __restrict__ feat,
                       unsigned short* __restrict__ Xb,
                       float* __restrict__ nz) {
  int row = blockIdx.x * 4 + (threadIdx.x >> 6);
  int lane = threadIdx.x & 63;
  float4 v = ((const float4*)feat)[(size_t)row * 64 + lane];
  float ssq = v.x * v.x + v.y * v.y + v.z * v.z + v.w * v.w;
#pragma unroll
  for (int off = 1; off < 64; off <<= 1) ssq += __shfl_xor(ssq, off);
  if (lane == 0) nz[row] = (ssq > 0.f) ? 1.f : 0.f;
  ushort4 p;
  p.x = f2bf(v.x); p.y = f2bf(v.y); p.z = f2bf(v.z); p.w = f2bf(v.w);
  ((ushort4*)Xb)[(size_t)row * 64 + lane] = p;
}

// ---------------------------------------------------------------------------
// raw_adj (256,512,512) fp32 -> adjB bf16 (RAW, unnormalized) + invrs[row]
// invrs = 1 / rowsum(raw_adj * nz)  (0 -> 1). One wave per adjacency row.
__global__ void k_adj(const float* __restrict__ adj, const float* __restrict__ nz,
                      unsigned short* __restrict__ adjB, float* __restrict__ invrs) {
  int row = blockIdx.x * 4 + (threadIdx.x >> 6);   // [0, 256*512)
  int lane = threadIdx.x & 63;
  int b = row >> 9;
  const float4* src = (const float4*)(adj + (size_t)row * 512);
  float4 a0 = src[lane * 2], a1 = src[lane * 2 + 1];
  const float4* nzp = (const float4*)(nz + (size_t)b * 512);
  float4 z0 = nzp[lane * 2], z1 = nzp[lane * 2 + 1];
  float s = a0.x * z0.x + a0.y * z0.y + a0.z * z0.z + a0.w * z0.w
          + a1.x * z1.x + a1.y * z1.y + a1.z * z1.z + a1.w * z1.w;
#pragma unroll
  for (int off = 1; off < 64; off <<= 1) s += __shfl_xor(s, off);
  if (lane == 0) {
    float rs = (s == 0.f) ? 1.f : s;
    invrs[row] = 1.f / rs;
  }
  uint4 p;
  p.x = (unsigned)f2bf(a0.x) | ((unsigned)f2bf(a0.y) << 16);
  p.y = (unsigned)f2bf(a0.z) | ((unsigned)f2bf(a0.w) << 16);
  p.z = (unsigned)f2bf(a1.x) | ((unsigned)f2bf(a1.y) << 16);
  p.w = (unsigned)f2bf(a1.z) | ((unsigned)f2bf(a1.w) << 16);
  ((uint4*)(adjB + (size_t)row * 512))[lane] = p;
}

// ---------------------------------------------------------------------------
// W0/W1/W2 (256,256) fp32 -> Wt bf16 TRANSPOSED: Wt[s][n][k] = W_s[k][n]
__global__ void k_wconv(const float* __restrict__ W0, const float* __restrict__ W1,
                        const float* __restrict__ W2, unsigned short* __restrict__ Wt) {
  int s = blockIdx.x >> 8;
  int n = blockIdx.x & 255;
  int k = threadIdx.x;
  const float* W = (s == 0) ? W0 : (s == 1) ? W1 : W2;
  Wt[(size_t)s * 65536 + n * 256 + k] = f2bf(W[(size_t)k * 256 + n]);
}

// ---------------------------------------------------------------------------
// Shared MFMA mainloop: 128x128 tile, BK=64, 4 waves (2x2 of 64x64).
// A: [M][K] bf16 row-major (ldaB bytes/row). B: [N][K] bf16 row-major (= op B
// transposed; ldbB bytes/row). LDS tiles 128x64 bf16 (16KB each) with XOR
// swizzle byte ^= ((row&7)<<4): 2-way bank aliasing only (free).
// global_load_lds dest is linear; sources are pre-swizzled per-lane.
__device__ __forceinline__ void gemm_tile(
    const char* Ag, int ldaB, const char* Bg, int ldbB, int nkt,
    char* ldsA, char* ldsB, f32x4 acc[4][4], int wm, int wn, int lane, int tid) {
  for (int kt = 0; kt < nkt; ++kt) {
#pragma unroll
    for (int q = 0; q < 4; ++q) {
      int P = (q * 256 + tid) * 16;          // physical LDS byte (linear)
      int L = P ^ (((P >> 7) & 7) << 4);     // logical byte (involution)
      int row = L >> 7, cb = L & 127;
      GLDS(Ag + (size_t)row * ldaB + kt * 128 + cb, ldsA + P);
      GLDS(Bg + (size_t)row * ldbB + kt * 128 + cb, ldsB + P);
    }
    __syncthreads();
#pragma unroll
    for (int ks = 0; ks < 2; ++ks) {
      short8 af[4], bfr[4];
      int c = ks * 64 + ((lane >> 4) << 4);  // k-byte offset for this lane
#pragma unroll
      for (int m = 0; m < 4; ++m) {
        int row = wm * 64 + m * 16 + (lane & 15);
        af[m] = *(const short8*)(ldsA + ((row * 128 + c) ^ ((row & 7) << 4)));
      }
#pragma unroll
      for (int n = 0; n < 4; ++n) {
        int row = wn * 64 + n * 16 + (lane & 15);
        bfr[n] = *(const short8*)(ldsB + ((row * 128 + c) ^ ((row & 7) << 4)));
      }
#pragma unroll
      for (int m = 0; m < 4; ++m)
#pragma unroll
        for (int n = 0; n < 4; ++n)
          acc[m][n] = __builtin_amdgcn_mfma_f32_16x16x32_bf16(af[m], bfr[n], acc[m][n], 0, 0, 0);
    }
    __syncthreads();
  }
}

// ---------------------------------------------------------------------------
// Z = X @ W  (M=131072, N=256, K=256), output written TRANSPOSED per block:
// Zt[b][h][node] so propagation B-tiles are contiguous. grid = 1024*2.
__global__ __launch_bounds__(256) void k_linear(const unsigned short* __restrict__ X,
                                                const unsigned short* __restrict__ Wt,
                                                unsigned short* __restrict__ Zt) {
  __shared__ char lds[32768];
  int tid = threadIdx.x, lane = tid & 63, wid = tid >> 6;
  int wm = wid >> 1, wn = wid & 1;
  int tm = blockIdx.x >> 1, tn = blockIdx.x & 1;
  const char* Ag = (const char*)(X + (size_t)tm * 128 * 256);
  const char* Bg = (const char*)(Wt + (size_t)tn * 128 * 256);
  f32x4 acc[4][4];
#pragma unroll
  for (int m = 0; m < 4; ++m)
#pragma unroll
    for (int n = 0; n < 4; ++n) { f32x4 z = {0.f, 0.f, 0.f, 0.f}; acc[m][n] = z; }
  gemm_tile(Ag, 512, Bg, 512, 4, lds, lds + 16384, acc, wm, wn, lane, tid);
  int b = tm >> 2;
  int node_base = ((tm & 3) * 128) + wm * 64;
  int h_base = tn * 128 + wn * 64;
#pragma unroll
  for (int m = 0; m < 4; ++m) {
    int node = node_base + m * 16 + ((lane >> 4) << 2);  // 4 consecutive nodes in regs
#pragma unroll
    for (int n = 0; n < 4; ++n) {
      int h = h_base + n * 16 + (lane & 15);
      f32x4 v = acc[m][n];
      ushort4 p;
      p.x = f2bf(v[0]); p.y = f2bf(v[1]); p.z = f2bf(v[2]); p.w = f2bf(v[3]);
      *(ushort4*)(Zt + ((size_t)b * 256 + h) * 512 + node) = p;  // 8B store
    }
  }
}

// ---------------------------------------------------------------------------
// X = relu(invrs[i] * (adjB[b] @ Z[b]))  (per block: M=512, N=256, K=512)
// A = raw bf16 adj rows; B = Zt rows (already [h][j]). grid = 256*4*2.
__global__ __launch_bounds__(256) void k_prop(const unsigned short* __restrict__ adjB,
                                              const unsigned short* __restrict__ Zt,
                                              const float* __restrict__ invrs,
                                              unsigned short* __restrict__ Xout) {
  __shared__ char lds[32768];
  int tid = threadIdx.x, lane = tid & 63, wid = tid >> 6;
  int wm = wid >> 1, wn = wid & 1;
  int b = blockIdx.x >> 3, tm = (blockIdx.x >> 1) & 3, tn = blockIdx.x & 1;
  const char* Ag = (const char*)(adjB + ((size_t)b * 512 + tm * 128) * 512);
  const char* Bg = (const char*)(Zt + ((size_t)b * 256 + tn * 128) * 512);
  f32x4 acc[4][4];
#pragma unroll
  for (int m = 0; m < 4; ++m)
#pragma unroll
    for (int n = 0; n < 4; ++n) { f32x4 z = {0.f, 0.f, 0.f, 0.f}; acc[m][n] = z; }
  gemm_tile(Ag, 1024, Bg, 1024, 8, lds, lds + 16384, acc, wm, wn, lane, tid);
  int node_base = tm * 128 + wm * 64;
  int h_base = tn * 128 + wn * 64;
#pragma unroll
  for (int m = 0; m < 4; ++m) {
    int node = node_base + m * 16 + ((lane >> 4) << 2);
    float4 s4 = *(const float4*)(invrs + (size_t)b * 512 + node);
    float sv[4] = {s4.x, s4.y, s4.z, s4.w};
#pragma unroll
    for (int n = 0; n < 4; ++n) {
      int h = h_base + n * 16 + (lane & 15);
#pragma unroll
      for (int r = 0; r < 4; ++r) {
        float v = acc[m][n][r] * sv[r];
        v = v > 0.f ? v : 0.f;
        Xout[((size_t)b * 512 + node + r) * 256 + h] = f2bf(v);
      }
    }
  }
}

// ---------------------------------------------------------------------------
// x3[b,:] = relu(invrs[b,0] * adjB[b,0,:] @ Z2[b])   (row-0-only propagation)
// Zt rows are contiguous in j -> each wave dots two contiguous 512-vectors.
__global__ void k_row0(const unsigned short* __restrict__ adjB,
                       const unsigned short* __restrict__ Zt,
                       const float* __restrict__ invrs, float* __restrict__ x3) {
  int b = blockIdx.x;
  int lane = threadIdx.x & 63, w = threadIdx.x >> 6;
  uint4 ap = ((const uint4*)(adjB + (size_t)b * 512 * 512))[lane];
  float a[8];
  a[0] = bf2f((unsigned short)(ap.x & 0xffff)); a[1] = bf2f((unsigned short)(ap.x >> 16));
  a[2] = bf2f((unsigned short)(ap.y & 0xffff)); a[3] = bf2f((unsigned short)(ap.y >> 16));
  a[4] = bf2f((unsigned short)(ap.z & 0xffff)); a[5] = bf2f((unsigned short)(ap.z >> 16));
  a[6] = bf2f((unsigned short)(ap.w & 0xffff)); a[7] = bf2f((unsigned short)(ap.w >> 16));
  float inv = invrs[(size_t)b * 512];
  for (int h = w; h < 256; h += 4) {
    uint4 zp = ((const uint4*)(Zt + ((size_t)b * 256 + h) * 512))[lane];
    float s = a[0] * bf2f((unsigned short)(zp.x & 0xffff)) + a[1] * bf2f((unsigned short)(zp.x >> 16))
            + a[2] * bf2f((unsigned short)(zp.y & 0xffff)) + a[3] * bf2f((unsigned short)(zp.y >> 16))
            + a[4] * bf2f((unsigned short)(zp.z & 0xffff)) + a[5] * bf2f((unsigned short)(zp.z >> 16))
            + a[6] * bf2f((unsigned short)(zp.w & 0xffff)) + a[7] * bf2f((unsigned short)(zp.w >> 16));
#pragma unroll
    for (int off = 1; off < 64; off <<= 1) s += __shfl_xor(s, off);
    if (lane == 0) {
      float v = s * inv;
      x3[b * 256 + h] = v > 0.f ? v : 0.f;
    }
  }
}

// ---------------------------------------------------------------------------
// out = x3 @ Wout  (256x256 @ 256x128, fp32). Trivial.
__global__ void k_out(const float* __restrict__ x3, const float* __restrict__ Wout,
                      float* __restrict__ out) {
  int b = blockIdx.x, o = threadIdx.x;
  float acc = 0.f;
  for (int k = 0; k < 256; ++k) acc += x3[b * 256 + k] * Wout[k * 128 + o];
  out[b * 128 + o] = acc;
}

// ---------------------------------------------------------------------------
extern "C" void kernel_launch(void* const* d_in, const int* in_sizes, int n_in,
                              void* d_out, int out_size, void* d_ws, size_t ws_size,
                              hipStream_t stream) {
  (void)in_sizes; (void)n_in; (void)out_size; (void)ws_size;
  const float* feat = (const float*)d_in[0];
  const float* adj  = (const float*)d_in[1];
  const float* W0   = (const float*)d_in[2];
  const float* W1   = (const float*)d_in[3];
  const float* W2   = (const float*)d_in[4];
  const float* Wout = (const float*)d_in[5];
  float* out = (float*)d_out;

  char* ws = (char*)d_ws;
  unsigned short* adjB = (unsigned short*)(ws);                 // 134217728 B
  unsigned short* Xbuf = (unsigned short*)(ws + 134217728);     //  67108864 B
  unsigned short* Zt   = (unsigned short*)(ws + 201326592);     //  67108864 B
  float* nzbuf         = (float*)(ws + 268435456);              //    524288 B
  float* invrs         = (float*)(ws + 268959744);              //    524288 B
  unsigned short* Wt   = (unsigned short*)(ws + 269484032);     //    393216 B
  float* x3            = (float*)(ws + 269877248);              //    262144 B
  // total ws usage: 270139392 bytes (~270 MB)

  k_feat<<<32768, 256, 0, stream>>>(feat, Xbuf, nzbuf);
  k_adj<<<32768, 256, 0, stream>>>(adj, nzbuf, adjB, invrs);
  k_wconv<<<768, 256, 0, stream>>>(W0, W1, W2, Wt);

  // step 0
  k_linear<<<2048, 256, 0, stream>>>(Xbuf, Wt + 0 * 65536, Zt);
  k_prop<<<2048, 256, 0, stream>>>(adjB, Zt, invrs, Xbuf);
  // step 1
  k_linear<<<2048, 256, 0, stream>>>(Xbuf, Wt + 1 * 65536, Zt);
  k_prop<<<2048, 256, 0, stream>>>(adjB, Zt, invrs, Xbuf);
  // step 2: linear, then row-0-only propagation
  k_linear<<<2048, 256, 0, stream>>>(Xbuf, Wt + 2 * 65536, Zt);
  k_row0<<<256, 256, 0, stream>>>(adjB, Zt, invrs, x3);

  k_out<<<256, 128, 0, stream>>>(x3, Wout, out);
}

// Round 2
// 347.545 us; speedup vs baseline: 1.3517x; 1.3517x over previous
//
#include <hip/hip_runtime.h>

// GCN: B=256 blocks, N=512 nodes, D_IN=D_HID=256, D_OUT=128, 3 steps.
// Schedule:
//   k_feat : feat fp32 -> Xbuf bf16, nz flags        (201 MB)
//   k_adj  : raw_adj fp32 -> adjN bf16 PRE-NORMALIZED by 1/rowsum  (402 MB)
//   k_wconv: W0,W1 -> bf16 transposed
//   2x { k_linear (Z=X@W, Zt transposed out), k_prop (X=relu(adjN@Z)) }
//   k_tail : out = relu((a0n @ X2) @ W2) @ Wout   (associativity: no 3rd linear)

typedef __attribute__((ext_vector_type(8))) short short8;
typedef __attribute__((ext_vector_type(4))) float f32x4;

__device__ __forceinline__ unsigned short f2bf(float x) {
  unsigned u = __float_as_uint(x);
  unsigned r = u + 0x7fffu + ((u >> 16) & 1u);
  return (unsigned short)(r >> 16);
}
__device__ __forceinline__ float bf2f(unsigned short b) {
  return __uint_as_float(((unsigned)b) << 16);
}

#define GLDS(g, l) __builtin_amdgcn_global_load_lds( \
    (const __attribute__((address_space(1))) void*)(g), \
    (__attribute__((address_space(3))) void*)(l), 16, 0, 0)

// ---------------------------------------------------------------------------
// feat (131072,256) fp32 -> Xbuf bf16, plus nz[row] = (||feat_row|| > 0)
__global__ void k_feat(const float* __restrict__ feat,
                       unsigned short* __restrict__ Xb,
                       float* __restrict__ nz) {
  int row = blockIdx.x * 4 + (threadIdx.x >> 6);
  int lane = threadIdx.x & 63;
  float4 v = ((const float4*)feat)[(size_t)row * 64 + lane];
  float ssq = v.x * v.x + v.y * v.y + v.z * v.z + v.w * v.w;
#pragma unroll
  for (int off = 1; off < 64; off <<= 1) ssq += __shfl_xor(ssq, off);
  if (lane == 0) nz[row] = (ssq > 0.f) ? 1.f : 0.f;
  ushort4 p;
  p.x = f2bf(v.x); p.y = f2bf(v.y); p.z = f2bf(v.z); p.w = f2bf(v.w);
  ((ushort4*)Xb)[(size_t)row * 64 + lane] = p;
}

// ---------------------------------------------------------------------------
// raw_adj (256,512,512) fp32 -> adjN bf16 normalized: adjN[i][j] = raw/rowsum
// rowsum = sum_j raw[i][j]*nz[j] (0 -> 1). One wave per row; butterfly gives
// every lane the sum, so scaling happens in-register in the same pass.
__global__ void k_adj(const float* __restrict__ adj, const float* __restrict__ nz,
                      unsigned short* __restrict__ adjN) {
  int row = blockIdx.x * 4 + (threadIdx.x >> 6);   // [0, 256*512)
  int lane = threadIdx.x & 63;
  int b = row >> 9;
  const float4* src = (const float4*)(adj + (size_t)row * 512);
  float4 a0 = src[lane * 2], a1 = src[lane * 2 + 1];
  const float4* nzp = (const float4*)(nz + (size_t)b * 512);
  float4 z0 = nzp[lane * 2], z1 = nzp[lane * 2 + 1];
  float s = a0.x * z0.x + a0.y * z0.y + a0.z * z0.z + a0.w * z0.w
          + a1.x * z1.x + a1.y * z1.y + a1.z * z1.z + a1.w * z1.w;
#pragma unroll
  for (int off = 1; off < 64; off <<= 1) s += __shfl_xor(s, off);
  float inv = 1.f / ((s == 0.f) ? 1.f : s);
  uint4 p;
  p.x = (unsigned)f2bf(a0.x * inv) | ((unsigned)f2bf(a0.y * inv) << 16);
  p.y = (unsigned)f2bf(a0.z * inv) | ((unsigned)f2bf(a0.w * inv) << 16);
  p.z = (unsigned)f2bf(a1.x * inv) | ((unsigned)f2bf(a1.y * inv) << 16);
  p.w = (unsigned)f2bf(a1.z * inv) | ((unsigned)f2bf(a1.w * inv) << 16);
  ((uint4*)(adjN + (size_t)row * 512))[lane] = p;
}

// ---------------------------------------------------------------------------
// W0/W1 (256,256) fp32 -> Wt bf16 TRANSPOSED: Wt[s][n][k] = W_s[k][n]
__global__ void k_wconv(const float* __restrict__ W0, const float* __restrict__ W1,
                        unsigned short* __restrict__ Wt) {
  int s = blockIdx.x >> 8;
  int n = blockIdx.x & 255;
  int k = threadIdx.x;
  const float* W = s ? W1 : W0;
  Wt[(size_t)s * 65536 + n * 256 + k] = f2bf(W[(size_t)k * 256 + n]);
}

// ---------------------------------------------------------------------------
// Shared MFMA mainloop: 128x128 tile, BK=64, 4 waves (2x2 of 64x64).
// A: [M][K] bf16 row-major (ldaB bytes/row). B: [N][K] bf16 row-major.
// LDS tiles 128x64 bf16 (16KB each), XOR swizzle byte ^= ((row&7)<<4).
__device__ __forceinline__ void gemm_tile(
    const char* Ag, int ldaB, const char* Bg, int ldbB, int nkt,
    char* ldsA, char* ldsB, f32x4 acc[4][4], int wm, int wn, int lane, int tid) {
  for (int kt = 0; kt < nkt; ++kt) {
#pragma unroll
    for (int q = 0; q < 4; ++q) {
      int P = (q * 256 + tid) * 16;          // physical LDS byte (linear)
      int L = P ^ (((P >> 7) & 7) << 4);     // logical byte (involution)
      int row = L >> 7, cb = L & 127;
      GLDS(Ag + (size_t)row * ldaB + kt * 128 + cb, ldsA + P);
      GLDS(Bg + (size_t)row * ldbB + kt * 128 + cb, ldsB + P);
    }
    __syncthreads();
#pragma unroll
    for (int ks = 0; ks < 2; ++ks) {
      short8 af[4], bfr[4];
      int c = ks * 64 + ((lane >> 4) << 4);
#pragma unroll
      for (int m = 0; m < 4; ++m) {
        int row = wm * 64 + m * 16 + (lane & 15);
        af[m] = *(const short8*)(ldsA + ((row * 128 + c) ^ ((row & 7) << 4)));
      }
#pragma unroll
      for (int n = 0; n < 4; ++n) {
        int row = wn * 64 + n * 16 + (lane & 15);
        bfr[n] = *(const short8*)(ldsB + ((row * 128 + c) ^ ((row & 7) << 4)));
      }
#pragma unroll
      for (int m = 0; m < 4; ++m)
#pragma unroll
        for (int n = 0; n < 4; ++n)
          acc[m][n] = __builtin_amdgcn_mfma_f32_16x16x32_bf16(af[m], bfr[n], acc[m][n], 0, 0, 0);
    }
    __syncthreads();
  }
}

// XCD-chunked bijective swizzle for grid 2048 (cpx = 256, 8 XCDs)
__device__ __forceinline__ int swz2048(int bid) {
  return (bid & 7) * 256 + (bid >> 3);
}

// ---------------------------------------------------------------------------
// Z = X @ W  (M=131072, N=256, K=256), output TRANSPOSED per block:
// Zt[b][h][node]. grid = 2048.
__global__ __launch_bounds__(256) void k_linear(const unsigned short* __restrict__ X,
                                                const unsigned short* __restrict__ Wt,
                                                unsigned short* __restrict__ Zt) {
  __shared__ char lds[32768];
  int tid = threadIdx.x, lane = tid & 63, wid = tid >> 6;
  int wm = wid >> 1, wn = wid & 1;
  int tile = swz2048(blockIdx.x);
  int tm = tile >> 1, tn = tile & 1;
  const char* Ag = (const char*)(X + (size_t)tm * 128 * 256);
  const char* Bg = (const char*)(Wt + (size_t)tn * 128 * 256);
  f32x4 acc[4][4];
#pragma unroll
  for (int m = 0; m < 4; ++m)
#pragma unroll
    for (int n = 0; n < 4; ++n) { f32x4 z = {0.f, 0.f, 0.f, 0.f}; acc[m][n] = z; }
  gemm_tile(Ag, 512, Bg, 512, 4, lds, lds + 16384, acc, wm, wn, lane, tid);
  int b = tm >> 2;
  int node_base = ((tm & 3) * 128) + wm * 64;
  int h_base = tn * 128 + wn * 64;
#pragma unroll
  for (int m = 0; m < 4; ++m) {
    int node = node_base + m * 16 + ((lane >> 4) << 2);
#pragma unroll
    for (int n = 0; n < 4; ++n) {
      int h = h_base + n * 16 + (lane & 15);
      f32x4 v = acc[m][n];
      ushort4 p;
      p.x = f2bf(v[0]); p.y = f2bf(v[1]); p.z = f2bf(v[2]); p.w = f2bf(v[3]);
      *(ushort4*)(Zt + ((size_t)b * 256 + h) * 512 + node) = p;
    }
  }
}

// ---------------------------------------------------------------------------
// X = relu(adjN[b] @ Z[b])  (per block: M=512, N=256, K=512). grid = 2048.
__global__ __launch_bounds__(256) void k_prop(const unsigned short* __restrict__ adjN,
                                              const unsigned short* __restrict__ Zt,
                                              unsigned short* __restrict__ Xout) {
  __shared__ char lds[32768];
  int tid = threadIdx.x, lane = tid & 63, wid = tid >> 6;
  int wm = wid >> 1, wn = wid & 1;
  int tile = swz2048(blockIdx.x);
  int b = tile >> 3, tm = (tile >> 1) & 3, tn = tile & 1;
  const char* Ag = (const char*)(adjN + ((size_t)b * 512 + tm * 128) * 512);
  const char* Bg = (const char*)(Zt + ((size_t)b * 256 + tn * 128) * 512);
  f32x4 acc[4][4];
#pragma unroll
  for (int m = 0; m < 4; ++m)
#pragma unroll
    for (int n = 0; n < 4; ++n) { f32x4 z = {0.f, 0.f, 0.f, 0.f}; acc[m][n] = z; }
  gemm_tile(Ag, 1024, Bg, 1024, 8, lds, lds + 16384, acc, wm, wn, lane, tid);
  int node_base = tm * 128 + wm * 64;
  int h_base = tn * 128 + wn * 64;
#pragma unroll
  for (int m = 0; m < 4; ++m) {
    int node = node_base + m * 16 + ((lane >> 4) << 2);
#pragma unroll
    for (int n = 0; n < 4; ++n) {
      int h = h_base + n * 16 + (lane & 15);
#pragma unroll
      for (int r = 0; r < 4; ++r) {
        float v = acc[m][n][r];
        v = v > 0.f ? v : 0.f;
        Xout[((size_t)b * 512 + node + r) * 256 + h] = f2bf(v);
      }
    }
  }
}

// ---------------------------------------------------------------------------
// Tail (one block per batch-block b):
//   y   = a0n @ X2_b            (1x512 @ 512x256, bf16 in, fp32 acc)
//   x3  = relu(y @ W2)          (fp32)
//   out = x3 @ Wout             (fp32)
__global__ __launch_bounds__(256) void k_tail(const unsigned short* __restrict__ adjN,
                                              const unsigned short* __restrict__ X2,
                                              const float* __restrict__ W2,
                                              const float* __restrict__ Wout,
                                              float* __restrict__ out) {
  __shared__ float aL[512];
  __shared__ float yL[8][256];
  __shared__ float y[256];
  __shared__ float x3[256];
  int b = blockIdx.x, tid = threadIdx.x;
  {
    const unsigned short* a0 = adjN + (size_t)b * 512 * 512;  // row 0 of block b
    ushort2 v = ((const ushort2*)a0)[tid];
    aL[tid * 2] = bf2f(v.x);
    aL[tid * 2 + 1] = bf2f(v.y);
  }
  __syncthreads();
  // phase 1: y[h] = sum_j a0n[j] * X2[j][h]; thread = (jg = tid>>5, hg = tid&31)
  {
    int hg = tid & 31, jg = tid >> 5;
    float acc[8] = {0.f, 0.f, 0.f, 0.f, 0.f, 0.f, 0.f, 0.f};
    const unsigned short* Xb = X2 + (size_t)b * 512 * 256;
    for (int jj = 0; jj < 64; ++jj) {
      int j = jj * 8 + jg;
      short8 xv = *(const short8*)(Xb + (size_t)j * 256 + hg * 8);
      float a = aL[j];
#pragma unroll
      for (int r = 0; r < 8; ++r) acc[r] += a * bf2f((unsigned short)xv[r]);
    }
#pragma unroll
    for (int r = 0; r < 8; ++r) yL[jg][hg * 8 + r] = acc[r];
  }
  __syncthreads();
  {
    float s = 0.f;
#pragma unroll
    for (int g = 0; g < 8; ++g) s += yL[g][tid];
    y[tid] = s;
  }
  __syncthreads();
  // phase 2: x3[o] = relu(sum_k y[k] * W2[k][o])
  {
    float s = 0.f;
    for (int k = 0; k < 256; ++k) s += y[k] * W2[(size_t)k * 256 + tid];
    x3[tid] = s > 0.f ? s : 0.f;
  }
  __syncthreads();
  // phase 3: out[b][o] = sum_h x3[h] * Wout[h][o]
  if (tid < 128) {
    float s = 0.f;
    for (int h = 0; h < 256; ++h) s += x3[h] * Wout[(size_t)h * 128 + tid];
    out[(size_t)b * 128 + tid] = s;
  }
}

// ---------------------------------------------------------------------------
extern "C" void kernel_launch(void* const* d_in, const int* in_sizes, int n_in,
                              void* d_out, int out_size, void* d_ws, size_t ws_size,
                              hipStream_t stream) {
  (void)in_sizes; (void)n_in; (void)out_size; (void)ws_size;
  const float* feat = (const float*)d_in[0];
  const float* adj  = (const float*)d_in[1];
  const float* W0   = (const float*)d_in[2];
  const float* W1   = (const float*)d_in[3];
  const float* W2   = (const float*)d_in[4];
  const float* Wout = (const float*)d_in[5];
  float* out = (float*)d_out;

  char* ws = (char*)d_ws;
  unsigned short* adjN = (unsigned short*)(ws);                 // 134217728 B
  unsigned short* Xbuf = (unsigned short*)(ws + 134217728);     //  67108864 B
  unsigned short* Zt   = (unsigned short*)(ws + 201326592);     //  67108864 B
  float* nzbuf         = (float*)(ws + 268435456);              //    524288 B
  unsigned short* Wt   = (unsigned short*)(ws + 268959744);     //    262144 B

  k_feat<<<32768, 256, 0, stream>>>(feat, Xbuf, nzbuf);
  k_adj<<<32768, 256, 0, stream>>>(adj, nzbuf, adjN);
  k_wconv<<<512, 256, 0, stream>>>(W0, W1, Wt);

  // step 0
  k_linear<<<2048, 256, 0, stream>>>(Xbuf, Wt, Zt);
  k_prop<<<2048, 256, 0, stream>>>(adjN, Zt, Xbuf);
  // step 1
  k_linear<<<2048, 256, 0, stream>>>(Xbuf, Wt + 65536, Zt);
  k_prop<<<2048, 256, 0, stream>>>(adjN, Zt, Xbuf);
  // step 2 (linear folded into tail via associativity) + output projection
  k_tail<<<256, 256, 0, stream>>>(adjN, Xbuf, W2, Wout, out);
}